// Round 1
// baseline (2184.519 us; speedup 1.0000x reference)
//
#include <hip/hip_runtime.h>
#include <cstdint>
#include <cstddef>

// SNN forward, fp32-faithful (r4/r5 passing semantics, bitwise-identical order):
//  - strict __fmul_rn/__fadd_rn LIF, ascending-k __fmaf_rn reductions, bias AFTER
//  - conv2 k-order (ic,kr,kc); x10 after bias; spike (vd-1)>0
//  - zero-term skipping bitwise-exact
// Round 7 deltas (perf only, order-preserving):
//  - barriers per step 9 -> 5: bitmap resets folded into scan wave (zero-after-read),
//    shuffle-based single-wave prefix scans (no scan barrier), end barrier removed
//  - output LI stage moved to idle threads 500-509 -> overlaps next step's conv1
//  - bm3 built with __ballot (full overwrite, no atomics/reset)
//  - wout cached in LDS (20 KB); out stage 8-deep 2-stage pipelined
//  - fc inner loop 16-wide, 2-deep software pipeline (load next batch during FMA chain)

#define TSTEPS 64
#define NB 256

__global__ __launch_bounds__(256)
void transpose_wfc(const float* __restrict__ wfc, float* __restrict__ wfcT) {
    int idx = blockIdx.x * 256 + threadIdx.x;     // [500,800] -> [800,500]
    if (idx < 500 * 800) {
        int o = idx / 800, j = idx % 800;
        wfcT[j * 500 + o] = wfc[idx];
    }
}

__global__ __launch_bounds__(512, 2)
void snn_forward(const float* __restrict__ x,      // [64,256,1,28,28]
                 const float* __restrict__ w1,     // [20,1,5,5]
                 const float* __restrict__ b1,     // [20]
                 const float* __restrict__ w2,     // [50,20,5,5]
                 const float* __restrict__ b2,     // [50]
                 const float* __restrict__ fcw,    // wfcT [800,500] (sj=500,so=1) or wfc [500,800]
                 long fc_sj, long fc_so,
                 const float* __restrict__ bfc,    // [500]
                 const float* __restrict__ wout,   // [10,500]
                 float* __restrict__ out)          // [64,256,10]
{
    const float CM = 0.1f;
    const float CS = 0.8f;

    const int b   = blockIdx.x;
    const int tid = threadIdx.x;

    // ---- LDS (~72 KB) ----
    __shared__ float xs[2][28 * 36];                 // double-buffered input tile
    __shared__ float p1[20 * 12 * 12];               // pooled L1 spikes, 0.0/1.0
    __shared__ float w1L[500];                       // conv1 weights
    __shared__ float woutL[5000];                    // wout [10,500] cached
    __shared__ unsigned int flagbits[20];            // 12 pooled-row flags per ic
    __shared__ unsigned int bm2[25];                 // pooled-L2 bitmap (800 bits)
    __shared__ unsigned int bm3[16];                 // L3 bitmap (500 bits)
    __shared__ unsigned short list2s[816];           // active fc-input indices (asc; +pad for spec reads)
    __shared__ unsigned short list3s[512];           // active L3 indices (asc; padded)
    __shared__ float v1L[8 * 400], i1L[8 * 400];     // L2 LIF state, plane [xx][tid]
    __shared__ float v2s[500], i2s[500];             // L3 LIF state
    __shared__ float vos[10],  ios[10];              // output LI state
    __shared__ int nn2s, nn3s;

    // ---- one-time init ----
    if (tid < 500) { v2s[tid] = 0.f; i2s[tid] = 0.f; w1L[tid] = w1[tid]; }
    if (tid < 10)  { vos[tid] = 0.f; ios[tid] = 0.f; }
    if (tid < 25)  bm2[tid] = 0u;
    if (tid < 20)  flagbits[tid] = 0u;
    if (tid < 16)  bm3[tid] = 0u;
    for (int i = tid; i < 3200; i += 512) { v1L[i] = 0.f; i1L[i] = 0.f; }
    for (int i = tid; i < 5000; i += 512) woutL[i] = wout[i];

    // staging index map (constant per thread)
    const int sr0 = tid / 28,         sc0_ = tid - sr0 * 28;           // elem tid
    const int has2 = (tid + 512) < 784;
    const int sr1 = (tid + 512) / 28, sc1_ = (tid + 512) - sr1 * 28;   // elem tid+512

    // prologue: stage ts=0
    {
        const float* xp = x + ((size_t)b) * 784;     // ts=0
        xs[0][sr0 * 36 + sc0_] = xp[tid];
        if (has2) xs[0][sr1 * 36 + sc1_] = xp[tid + 512];
    }

    // ---- layer-1 mapping: 480 threads = 20 ch x 12 pool-rows x 2 col-halves ----
    const int l1  = (tid < 480);
    const int c   = tid / 24;
    const int sub = tid % 24;
    const int pr  = sub >> 1;
    const int chh = sub & 1;
    const int r0  = pr * 2;
    const int c0  = chh * 12;

    float v0a[12], v0b[12], i0a[12], i0b[12];        // L1 state (registers, 48)
    #pragma unroll
    for (int j = 0; j < 12; ++j) { v0a[j] = 0.f; v0b[j] = 0.f; i0a[j] = 0.f; i0b[j] = 0.f; }

    // ---- layer-2 mapping: 400 threads = 50 oc x 8 out-rows; 8 cols each ----
    const int l2  = (tid < 400);
    const int oc2 = tid >> 3;
    const int y2  = tid & 7;
    const float bias2 = l2 ? b2[oc2] : 0.f;
    const float bias1 = l1 ? b1[c] : 0.f;

    __syncthreads();   // init + xs[0] ready

    for (int ts = 0; ts < TSTEPS; ++ts) {
        const int cur = ts & 1, nxt = cur ^ 1;

        // prefetch next step's x into registers (latency overlaps conv1)
        float xpre0 = 0.f, xpre1 = 0.f;
        if (ts + 1 < TSTEPS) {
            const float* xpn = x + ((size_t)(ts + 1) * NB + b) * 784;
            xpre0 = xpn[tid];
            if (has2) xpre1 = xpn[tid + 512];
        }

        // ========== conv1 (fma, (kr,kc) asc, bias AFTER) + LIF1 + pool1 ==========
        if (l1) {
            float acc0[12], acc1[12];
            #pragma unroll
            for (int j = 0; j < 12; ++j) { acc0[j] = 0.f; acc1[j] = 0.f; }
            float wc[5], wp[5];
            #pragma unroll
            for (int ir = 0; ir < 6; ++ir) {
                float xr[16];
                const float4* rp = (const float4*)(xs[cur] + (r0 + ir) * 36 + c0);
                #pragma unroll
                for (int q = 0; q < 4; ++q) {
                    float4 f = rp[q];
                    xr[4*q+0] = f.x; xr[4*q+1] = f.y; xr[4*q+2] = f.z; xr[4*q+3] = f.w;
                }
                if (ir < 5) {                      // rolling weight window (same values/order)
                    #pragma unroll
                    for (int k = 0; k < 5; ++k) wc[k] = w1L[c * 25 + ir * 5 + k];
                    #pragma unroll
                    for (int kc = 0; kc < 5; ++kc) {
                        const float w = wc[kc];
                        #pragma unroll
                        for (int j = 0; j < 12; ++j)
                            acc0[j] = __fmaf_rn(w, xr[j + kc], acc0[j]);
                    }
                }
                if (ir >= 1) {                     // out row r0+1, kr = ir-1 -> wp
                    #pragma unroll
                    for (int kc = 0; kc < 5; ++kc) {
                        const float w = wp[kc];
                        #pragma unroll
                        for (int j = 0; j < 12; ++j)
                            acc1[j] = __fmaf_rn(w, xr[j + kc], acc1[j]);
                    }
                }
                #pragma unroll
                for (int k = 0; k < 5; ++k) wp[k] = wc[k];
            }
            unsigned int zb0 = 0, zb1 = 0;
            #pragma unroll
            for (int j = 0; j < 12; ++j) {
                const float inp = __fadd_rn(acc0[j], bias1);
                const float vd  = __fadd_rn(v0a[j], __fmul_rn(CM, __fsub_rn(i0a[j], v0a[j])));
                const float id  = __fmul_rn(i0a[j], CS);
                const int z = (__fsub_rn(vd, 1.0f) > 0.0f);
                v0a[j] = z ? 0.f : vd;
                i0a[j] = __fadd_rn(id, inp);
                zb0 |= (unsigned)z << j;
            }
            #pragma unroll
            for (int j = 0; j < 12; ++j) {
                const float inp = __fadd_rn(acc1[j], bias1);
                const float vd  = __fadd_rn(v0b[j], __fmul_rn(CM, __fsub_rn(i0b[j], v0b[j])));
                const float id  = __fmul_rn(i0b[j], CS);
                const int z = (__fsub_rn(vd, 1.0f) > 0.0f);
                v0b[j] = z ? 0.f : vd;
                i0b[j] = __fadd_rn(id, inp);
                zb1 |= (unsigned)z << j;
            }
            const unsigned int zp = zb0 | zb1;
            #pragma unroll
            for (int jj = 0; jj < 6; ++jj)
                p1[(c * 12 + pr) * 12 + chh * 6 + jj] = ((zp >> (2 * jj)) & 3u) ? 1.0f : 0.0f;
            if (zp) atomicOr(&flagbits[c], 1u << pr);
        }
        // write prefetched x to the other buffer (read next step)
        if (ts + 1 < TSTEPS) {
            xs[nxt][sr0 * 36 + sc0_] = xpre0;
            if (has2) xs[nxt][sr1 * 36 + sc1_] = xpre1;
        }
        __syncthreads();   // (B) p1, flagbits ready

        // ========== conv2 (fma, (ic,kr,kc) asc, bias AFTER, x10 AFTER) + LIF2 ==========
        if (l2) {
            float acc[8];
            #pragma unroll
            for (int xx = 0; xx < 8; ++xx) acc[xx] = 0.f;
            for (int ic = 0; ic < 20; ++ic) {
                const unsigned int win = (flagbits[ic] >> y2) & 31u;   // 5-row window mask
                if (!win) continue;                                     // all-zero: exact skip
                #pragma unroll
                for (int kr = 0; kr < 5; ++kr) {
                    if (!(win & (1u << kr))) continue;                  // exact skip
                    const float4* pp = (const float4*)(p1 + (ic * 12 + y2 + kr) * 12);
                    float4 f0 = pp[0], f1 = pp[1], f2 = pp[2];
                    const float pv[12] = { f0.x,f0.y,f0.z,f0.w, f1.x,f1.y,f1.z,f1.w, f2.x,f2.y,f2.z,f2.w };
                    const float* wrow = w2 + ((oc2 * 20 + ic) * 5 + kr) * 5;
                    const float w0 = wrow[0], w1_ = wrow[1], w2_ = wrow[2], w3_ = wrow[3], w4_ = wrow[4];
                    #pragma unroll
                    for (int xx = 0; xx < 8; ++xx) acc[xx] = __fmaf_rn(w0, pv[xx],     acc[xx]);
                    #pragma unroll
                    for (int xx = 0; xx < 8; ++xx) acc[xx] = __fmaf_rn(w1_, pv[xx + 1], acc[xx]);
                    #pragma unroll
                    for (int xx = 0; xx < 8; ++xx) acc[xx] = __fmaf_rn(w2_, pv[xx + 2], acc[xx]);
                    #pragma unroll
                    for (int xx = 0; xx < 8; ++xx) acc[xx] = __fmaf_rn(w3_, pv[xx + 3], acc[xx]);
                    #pragma unroll
                    for (int xx = 0; xx < 8; ++xx) acc[xx] = __fmaf_rn(w4_, pv[xx + 4], acc[xx]);
                }
            }
            unsigned int pb = 0;                                        // pooled bits for bm2
            const unsigned int bitbase = (unsigned)((oc2 & 1) * 16 + (y2 >> 1) * 4);
            #pragma unroll
            for (int xx = 0; xx < 8; ++xx) {
                const float vold = v1L[xx * 400 + tid];
                const float iold = i1L[xx * 400 + tid];
                const float inp  = __fmul_rn(10.0f, __fadd_rn(acc[xx], bias2));
                const float vd   = __fadd_rn(vold, __fmul_rn(CM, __fsub_rn(iold, vold)));
                const float id   = __fmul_rn(iold, CS);
                const int z = (__fsub_rn(vd, 1.0f) > 0.0f);
                v1L[xx * 400 + tid] = z ? 0.f : vd;
                i1L[xx * 400 + tid] = __fadd_rn(id, inp);
                if (z) pb |= 1u << (bitbase + (xx >> 1));
            }
            if (pb) atomicOr(&bm2[oc2 >> 1], pb);
        }
        __syncthreads();   // (C) bm2 complete

        // ---- scan2 (single wave, shuffle prefix): bm2 -> list2s; zero bm2/flagbits ----
        if (tid < 64) {
            unsigned int bits = (tid < 25) ? bm2[tid] : 0u;
            if (tid < 25) bm2[tid] = 0u;                 // consumed; next writer is conv2(s+1)
            if (tid >= 32 && tid < 52) flagbits[tid - 32] = 0u;  // consumed at (C); next writer conv1(s+1)
            int cnt = __popc(bits);
            int inc = cnt;
            #pragma unroll
            for (int d = 1; d < 32; d <<= 1) {
                int n = __shfl_up(inc, d);
                if (tid >= d) inc += n;
            }
            int off = inc - cnt;                          // exclusive prefix
            if (tid == 24) nn2s = inc;
            while (bits) {
                const int bb = __builtin_ctz(bits);
                bits &= bits - 1;
                list2s[off++] = (unsigned short)(tid * 32 + bb);
            }
        }
        __syncthreads();   // (E) list2s ready, bitmaps cleared

        // ========== fc 800->500 (fma, j asc, bias AFTER) + LIF3 ==========
        if (tid < 500) {
            const int nn2 = nn2s;
            const long cbase = (long)tid * fc_so;
            float acc = 0.f;
            int k = 0;
            const int kfull = nn2 & ~15;
            if (kfull > 0) {                              // 16-wide, 2-deep pipeline
                float a[16];
                #pragma unroll
                for (int q = 0; q < 16; ++q)
                    a[q] = fcw[(long)list2s[q] * fc_sj + cbase];
                for (k = 16; k < kfull; k += 16) {
                    float bv[16];
                    #pragma unroll
                    for (int q = 0; q < 16; ++q)
                        bv[q] = fcw[(long)list2s[k + q] * fc_sj + cbase];
                    #pragma unroll
                    for (int q = 0; q < 16; ++q)
                        acc = __fmaf_rn(1.0f, a[q], acc);
                    #pragma unroll
                    for (int q = 0; q < 16; ++q)
                        a[q] = bv[q];
                }
                #pragma unroll
                for (int q = 0; q < 16; ++q)
                    acc = __fmaf_rn(1.0f, a[q], acc);
                k = kfull;
            }
            {                                             // tail <=15: preload then asc chain
                const int rem = nn2 - k;
                float t[15];
                #pragma unroll
                for (int q = 0; q < 15; ++q)
                    t[q] = (q < rem) ? fcw[(long)list2s[k + q] * fc_sj + cbase] : 0.f;
                #pragma unroll
                for (int q = 0; q < 15; ++q)
                    if (q < rem) acc = __fmaf_rn(1.0f, t[q], acc);
            }
            const float inp = __fadd_rn(acc, bfc[tid]);
            const float vd  = __fadd_rn(v2s[tid], __fmul_rn(CM, __fsub_rn(i2s[tid], v2s[tid])));
            const float id  = __fmul_rn(i2s[tid], CS);
            const int z = (__fsub_rn(vd, 1.0f) > 0.0f);
            v2s[tid] = z ? 0.f : vd;
            i2s[tid] = __fadd_rn(id, inp);
            const unsigned long long m = __ballot(z);     // full-word overwrite, no atomics
            if ((tid & 63) == 0) {
                bm3[(tid >> 5)]     = (unsigned int)m;
                bm3[(tid >> 5) + 1] = (unsigned int)(m >> 32);
            }
        }
        __syncthreads();   // (F) bm3 complete

        // ---- scan3 (single wave, shuffle prefix): bm3 -> list3s ----
        if (tid < 64) {
            unsigned int bits = (tid < 16) ? bm3[tid] : 0u;
            int cnt = __popc(bits);
            int inc = cnt;
            #pragma unroll
            for (int d = 1; d < 16; d <<= 1) {
                int n = __shfl_up(inc, d);
                if (tid >= d) inc += n;
            }
            int off = inc - cnt;
            if (tid == 15) nn3s = inc;
            while (bits) {
                const int bb = __builtin_ctz(bits);
                bits &= bits - 1;
                list3s[off++] = (unsigned short)(tid * 32 + bb);
            }
        }
        __syncthreads();   // (H) list3s ready

        // ========== output LI cell (strict) — idle threads 500-509; overlaps next conv1 ==========
        {
            const int otid = tid - 500;
            if (otid >= 0 && otid < 10) {
                const int nn3 = nn3s;
                float acc = 0.f;
                int k = 0;
                const int kfull = nn3 & ~7;
                if (kfull > 0) {                          // 8-wide, 2-deep pipeline (LDS)
                    float a[8];
                    #pragma unroll
                    for (int q = 0; q < 8; ++q)
                        a[q] = woutL[otid * 500 + list3s[q]];
                    for (k = 8; k < kfull; k += 8) {
                        float bv[8];
                        #pragma unroll
                        for (int q = 0; q < 8; ++q)
                            bv[q] = woutL[otid * 500 + list3s[k + q]];
                        #pragma unroll
                        for (int q = 0; q < 8; ++q)
                            acc = __fmaf_rn(1.0f, a[q], acc);
                        #pragma unroll
                        for (int q = 0; q < 8; ++q)
                            a[q] = bv[q];
                    }
                    #pragma unroll
                    for (int q = 0; q < 8; ++q)
                        acc = __fmaf_rn(1.0f, a[q], acc);
                    k = kfull;
                }
                {
                    const int rem = nn3 - k;
                    float t[7];
                    #pragma unroll
                    for (int q = 0; q < 7; ++q)
                        t[q] = (q < rem) ? woutL[otid * 500 + list3s[k + q]] : 0.f;
                    #pragma unroll
                    for (int q = 0; q < 7; ++q)
                        if (q < rem) acc = __fmaf_rn(1.0f, t[q], acc);
                }
                const float vn = __fadd_rn(vos[otid], __fmul_rn(CM, __fsub_rn(ios[otid], vos[otid])));
                ios[otid] = __fadd_rn(__fmul_rn(ios[otid], CS), acc);
                vos[otid] = vn;
                out[((size_t)ts * NB + b) * 10 + otid] = vn;
            }
        }
        // no end barrier: out-stage state is private to threads 500-509; its inputs
        // (list3s, nn3s, woutL) are not rewritten until after B(s+1)..F(s+1).
    }
}

extern "C" void kernel_launch(void* const* d_in, const int* in_sizes, int n_in,
                              void* d_out, int out_size, void* d_ws, size_t ws_size,
                              hipStream_t stream)
{
    const float* x    = (const float*)d_in[0];
    const float* w1   = (const float*)d_in[1];
    const float* b1   = (const float*)d_in[2];
    const float* w2   = (const float*)d_in[3];
    const float* b2   = (const float*)d_in[4];
    const float* wfc  = (const float*)d_in[5];
    const float* bfc  = (const float*)d_in[6];
    const float* wout = (const float*)d_in[7];
    float* out = (float*)d_out;

    const float* fcptr = wfc;
    long sj = 1, so = 800;
    if (ws_size >= (size_t)500 * 800 * sizeof(float)) {
        float* wfcT = (float*)d_ws;
        transpose_wfc<<<(500 * 800 + 255) / 256, 256, 0, stream>>>(wfc, wfcT);
        fcptr = wfcT; sj = 500; so = 1;
    }

    snn_forward<<<NB, 512, 0, stream>>>(x, w1, b1, w2, b2, fcptr, sj, so, bfc, wout, out);
}

// Round 2
// 1588.649 us; speedup vs baseline: 1.3751x; 1.3751x over previous
//
#include <hip/hip_runtime.h>
#include <cstdint>
#include <cstddef>

// SNN forward, fp32-faithful (bitwise-identical accumulation order vs r4/r5 semantics):
//  - strict __fmul_rn/__fadd_rn LIF, ascending-k __fmaf_rn reductions, bias AFTER
//  - conv2 k-order (ic,kr,kc); x10 after bias; spike (vd-1)>0
// Round 8 deltas (perf only, order-preserving):
//  - conv2 DENSE + 2-deep software pipeline (rows + next-ic weights prefetched).
//    Zero rows give fma(w,0,acc)==acc bitwise -> dense == sparse result exactly.
//    Removes flagbits machinery entirely.
//  - fc: scan2 emits pre-scaled byte offsets; readfirstlane -> SGPR row base
//    (global_load v,voff,s[base]); 32-wide ping-pong pipeline, no reg copies.
//  - LIF2 (v1/i1), LIF3 (v2/i2), out LI state moved LDS -> registers (occupancy
//    is grid-pinned at 8 waves/CU; VGPR headroom to 256 is free).
//  - LDS ~47 KB (was 74 KB)

#define TSTEPS 64
#define NB 256

#define RFL(v) __builtin_amdgcn_readfirstlane(v)

__global__ __launch_bounds__(256)
void transpose_wfc(const float* __restrict__ wfc, float* __restrict__ wfcT) {
    int idx = blockIdx.x * 256 + threadIdx.x;     // [500,800] -> [800,500]
    if (idx < 500 * 800) {
        int o = idx / 800, j = idx % 800;
        wfcT[j * 500 + o] = wfc[idx];
    }
}

__global__ __launch_bounds__(512, 2)
void snn_forward(const float* __restrict__ x,      // [64,256,1,28,28]
                 const float* __restrict__ w1,     // [20,1,5,5]
                 const float* __restrict__ b1,     // [20]
                 const float* __restrict__ w2,     // [50,20,5,5]
                 const float* __restrict__ b2,     // [50]
                 const float* __restrict__ fcw,    // wfcT [800,500] (sj=500,so=1) or wfc [500,800]
                 long fc_sj, long fc_so,
                 const float* __restrict__ bfc,    // [500]
                 const float* __restrict__ wout,   // [10,500]
                 float* __restrict__ out)          // [64,256,10]
{
    const float CM = 0.1f;
    const float CS = 0.8f;

    const int b   = blockIdx.x;
    const int tid = threadIdx.x;

    // ---- LDS (~47 KB) ----
    __shared__ float xs[2][28 * 36];                 // double-buffered input tile
    __shared__ float p1[20 * 12 * 12];               // pooled L1 spikes, 0.0/1.0
    __shared__ float w1L[500];                       // conv1 weights
    __shared__ float woutL[5000];                    // wout [10,500] cached
    __shared__ unsigned int bm2[25];                 // pooled-L2 bitmap (800 bits)
    __shared__ unsigned int bm3[16];                 // L3 bitmap (500 bits)
    __shared__ int list2i[816];                      // active fc rows as BYTE offsets (asc)
    __shared__ unsigned short list3s[512];           // active L3 indices (asc)
    __shared__ int nn2s, nn3s;

    // ---- one-time init ----
    if (tid < 500) w1L[tid] = w1[tid];
    if (tid < 25)  bm2[tid] = 0u;
    for (int i = tid; i < 5000; i += 512) woutL[i] = wout[i];

    // staging index map (constant per thread)
    const int sr0 = tid / 28,         sc0_ = tid - sr0 * 28;           // elem tid
    const int has2 = (tid + 512) < 784;
    const int sr1 = (tid + 512) / 28, sc1_ = (tid + 512) - sr1 * 28;   // elem tid+512

    // prologue: stage ts=0
    {
        const float* xp = x + ((size_t)b) * 784;     // ts=0
        xs[0][sr0 * 36 + sc0_] = xp[tid];
        if (has2) xs[0][sr1 * 36 + sc1_] = xp[tid + 512];
    }

    // ---- layer-1 mapping: 480 threads = 20 ch x 12 pool-rows x 2 col-halves ----
    const int l1  = (tid < 480);
    const int c   = tid / 24;
    const int sub = tid % 24;
    const int pr  = sub >> 1;
    const int chh = sub & 1;
    const int r0  = pr * 2;
    const int c0  = chh * 12;

    float v0a[12], v0b[12], i0a[12], i0b[12];        // L1 state (registers)
    #pragma unroll
    for (int j = 0; j < 12; ++j) { v0a[j] = 0.f; v0b[j] = 0.f; i0a[j] = 0.f; i0b[j] = 0.f; }

    // ---- layer-2 mapping: 400 threads = 50 oc x 8 out-rows; 8 cols each ----
    const int l2  = (tid < 400);
    const int oc2 = tid >> 3;
    const int y2  = tid & 7;
    const float bias2 = l2 ? b2[oc2] : 0.f;
    const float bias1 = l1 ? b1[c] : 0.f;
    const float* w2base = w2 + (size_t)oc2 * 500;    // [20][25] for this oc

    float vL2[8], iL2[8];                            // L2 LIF state (registers)
    #pragma unroll
    for (int q = 0; q < 8; ++q) { vL2[q] = 0.f; iL2[q] = 0.f; }

    float vL3 = 0.f, iL3 = 0.f;                      // L3 LIF state (registers)
    const float bfc_r = (tid < 500) ? bfc[tid] : 0.f;

    float vO = 0.f, iO = 0.f;                        // output LI state (registers)

    // fc addressing (scalar base comes from readfirstlane'd list2i entries)
    const char* __restrict__ fcb = (const char*)fcw;
    const int coff = (int)((long)tid * fc_so) * 4;   // per-thread column byte offset

    __syncthreads();   // init + xs[0] ready

    for (int ts = 0; ts < TSTEPS; ++ts) {
        const int cur = ts & 1, nxt = cur ^ 1;

        // prefetch next step's x into registers (latency overlaps conv1)
        float xpre0 = 0.f, xpre1 = 0.f;
        if (ts + 1 < TSTEPS) {
            const float* xpn = x + ((size_t)(ts + 1) * NB + b) * 784;
            xpre0 = xpn[tid];
            if (has2) xpre1 = xpn[tid + 512];
        }

        // issue conv2's ic=0 weight loads now (independent of this step's p1;
        // latency hides under conv1)
        float wcur[25];
        if (l2) {
            #pragma unroll
            for (int q = 0; q < 25; ++q) wcur[q] = w2base[q];
        }

        // ========== conv1 (fma, (kr,kc) asc, bias AFTER) + LIF1 + pool1 ==========
        if (l1) {
            float acc0[12], acc1[12];
            #pragma unroll
            for (int j = 0; j < 12; ++j) { acc0[j] = 0.f; acc1[j] = 0.f; }
            float wc[5], wp[5];
            #pragma unroll
            for (int ir = 0; ir < 6; ++ir) {
                float xr[16];
                const float4* rp = (const float4*)(xs[cur] + (r0 + ir) * 36 + c0);
                #pragma unroll
                for (int q = 0; q < 4; ++q) {
                    float4 f = rp[q];
                    xr[4*q+0] = f.x; xr[4*q+1] = f.y; xr[4*q+2] = f.z; xr[4*q+3] = f.w;
                }
                if (ir < 5) {                      // rolling weight window (same values/order)
                    #pragma unroll
                    for (int k = 0; k < 5; ++k) wc[k] = w1L[c * 25 + ir * 5 + k];
                    #pragma unroll
                    for (int kc = 0; kc < 5; ++kc) {
                        const float w = wc[kc];
                        #pragma unroll
                        for (int j = 0; j < 12; ++j)
                            acc0[j] = __fmaf_rn(w, xr[j + kc], acc0[j]);
                    }
                }
                if (ir >= 1) {                     // out row r0+1, kr = ir-1 -> wp
                    #pragma unroll
                    for (int kc = 0; kc < 5; ++kc) {
                        const float w = wp[kc];
                        #pragma unroll
                        for (int j = 0; j < 12; ++j)
                            acc1[j] = __fmaf_rn(w, xr[j + kc], acc1[j]);
                    }
                }
                #pragma unroll
                for (int k = 0; k < 5; ++k) wp[k] = wc[k];
            }
            unsigned int zb0 = 0, zb1 = 0;
            #pragma unroll
            for (int j = 0; j < 12; ++j) {
                const float inp = __fadd_rn(acc0[j], bias1);
                const float vd  = __fadd_rn(v0a[j], __fmul_rn(CM, __fsub_rn(i0a[j], v0a[j])));
                const float id  = __fmul_rn(i0a[j], CS);
                const int z = (__fsub_rn(vd, 1.0f) > 0.0f);
                v0a[j] = z ? 0.f : vd;
                i0a[j] = __fadd_rn(id, inp);
                zb0 |= (unsigned)z << j;
            }
            #pragma unroll
            for (int j = 0; j < 12; ++j) {
                const float inp = __fadd_rn(acc1[j], bias1);
                const float vd  = __fadd_rn(v0b[j], __fmul_rn(CM, __fsub_rn(i0b[j], v0b[j])));
                const float id  = __fmul_rn(i0b[j], CS);
                const int z = (__fsub_rn(vd, 1.0f) > 0.0f);
                v0b[j] = z ? 0.f : vd;
                i0b[j] = __fadd_rn(id, inp);
                zb1 |= (unsigned)z << j;
            }
            const unsigned int zp = zb0 | zb1;
            #pragma unroll
            for (int jj = 0; jj < 6; ++jj)
                p1[(c * 12 + pr) * 12 + chh * 6 + jj] = ((zp >> (2 * jj)) & 3u) ? 1.0f : 0.0f;
        }
        // write prefetched x to the other buffer (read next step)
        if (ts + 1 < TSTEPS) {
            xs[nxt][sr0 * 36 + sc0_] = xpre0;
            if (has2) xs[nxt][sr1 * 36 + sc1_] = xpre1;
        }
        __syncthreads();   // (B) p1 ready

        // ===== conv2 DENSE, 2-deep pipelined (fma, (ic,kr,kc) asc, bias AFTER, x10 AFTER) + LIF2 =====
        // Zero p1 rows contribute fma(w, 0.0, acc) == acc bitwise -> identical to row-skip.
        if (l2) {
            float acc[8];
            #pragma unroll
            for (int xx = 0; xx < 8; ++xx) acc[xx] = 0.f;

            float4 ra, rb, rc;                       // current row (12 floats)
            {
                const float4* pp = (const float4*)(p1 + y2 * 12);   // (ic=0,kr=0)
                ra = pp[0]; rb = pp[1]; rc = pp[2];
            }
            float wnxt[25];

            for (int ic = 0; ic < 20; ++ic) {
                if (ic + 1 < 20) {                   // issue next-ic weights early
                    #pragma unroll
                    for (int q = 0; q < 25; ++q) wnxt[q] = w2base[(ic + 1) * 25 + q];
                }
                #pragma unroll
                for (int kr = 0; kr < 5; ++kr) {
                    float4 na, nb, nc;
                    const bool last = (ic == 19) && (kr == 4);
                    if (!last) {                     // issue next row load
                        const int nic = (kr == 4) ? ic + 1 : ic;
                        const int nkr = (kr == 4) ? 0 : kr + 1;
                        const float4* pp = (const float4*)(p1 + (nic * 12 + y2 + nkr) * 12);
                        na = pp[0]; nb = pp[1]; nc = pp[2];
                    }
                    const float pv[12] = { ra.x,ra.y,ra.z,ra.w, rb.x,rb.y,rb.z,rb.w, rc.x,rc.y,rc.z,rc.w };
                    const float w0  = wcur[kr*5+0], w1_ = wcur[kr*5+1], w2_ = wcur[kr*5+2];
                    const float w3_ = wcur[kr*5+3], w4_ = wcur[kr*5+4];
                    #pragma unroll
                    for (int xx = 0; xx < 8; ++xx) acc[xx] = __fmaf_rn(w0, pv[xx],     acc[xx]);
                    #pragma unroll
                    for (int xx = 0; xx < 8; ++xx) acc[xx] = __fmaf_rn(w1_, pv[xx + 1], acc[xx]);
                    #pragma unroll
                    for (int xx = 0; xx < 8; ++xx) acc[xx] = __fmaf_rn(w2_, pv[xx + 2], acc[xx]);
                    #pragma unroll
                    for (int xx = 0; xx < 8; ++xx) acc[xx] = __fmaf_rn(w3_, pv[xx + 3], acc[xx]);
                    #pragma unroll
                    for (int xx = 0; xx < 8; ++xx) acc[xx] = __fmaf_rn(w4_, pv[xx + 4], acc[xx]);
                    if (!last) { ra = na; rb = nb; rc = nc; }
                }
                if (ic + 1 < 20) {
                    #pragma unroll
                    for (int q = 0; q < 25; ++q) wcur[q] = wnxt[q];
                }
            }

            unsigned int pb = 0;                     // pooled bits for bm2
            const unsigned int bitbase = (unsigned)((oc2 & 1) * 16 + (y2 >> 1) * 4);
            #pragma unroll
            for (int xx = 0; xx < 8; ++xx) {
                const float inp = __fmul_rn(10.0f, __fadd_rn(acc[xx], bias2));
                const float vd  = __fadd_rn(vL2[xx], __fmul_rn(CM, __fsub_rn(iL2[xx], vL2[xx])));
                const float id  = __fmul_rn(iL2[xx], CS);
                const int z = (__fsub_rn(vd, 1.0f) > 0.0f);
                vL2[xx] = z ? 0.f : vd;
                iL2[xx] = __fadd_rn(id, inp);
                if (z) pb |= 1u << (bitbase + (xx >> 1));
            }
            if (pb) atomicOr(&bm2[oc2 >> 1], pb);
        }
        __syncthreads();   // (C) bm2 complete

        // ---- scan2 (single wave, shuffle prefix): bm2 -> list2i (byte offsets); zero bm2 ----
        if (tid < 64) {
            unsigned int bits = (tid < 25) ? bm2[tid] : 0u;
            if (tid < 25) bm2[tid] = 0u;             // consumed; next writer conv2(s+1)
            int cnt = __popc(bits);
            int inc = cnt;
            #pragma unroll
            for (int d = 1; d < 32; d <<= 1) {
                int n = __shfl_up(inc, d);
                if (tid >= d) inc += n;
            }
            int off = inc - cnt;                     // exclusive prefix
            if (tid == 24) nn2s = inc;
            const int jstride = (int)fc_sj * 4;
            const int base = tid * 32;
            while (bits) {
                const int bb = __builtin_ctz(bits);
                bits &= bits - 1;
                list2i[off++] = (base + bb) * jstride;
            }
        }
        __syncthreads();   // (E) list2i ready

        // ========== fc 800->500 (fma, j asc, bias AFTER) + LIF3 ==========
        if (tid < 500) {
            const int nn2 = nn2s;
            float acc = 0.f;
            int k = 0;

#define FC_LOAD32(dst, kk) do { _Pragma("unroll") \
            for (int q_ = 0; q_ < 32; ++q_) { \
                const int o_ = RFL(list2i[(kk) + q_]); \
                dst[q_] = *(const float*)(fcb + (size_t)(unsigned)(o_ + coff)); } } while (0)
#define FC_FMA32(src) do { _Pragma("unroll") \
            for (int q_ = 0; q_ < 32; ++q_) acc = __fmaf_rn(1.0f, src[q_], acc); } while (0)

            const int nb32 = nn2 >> 5;               // full 32-batches
            if (nb32 >= 1) {                          // ping-pong, no reg copies
                float A[32], B[32];
                FC_LOAD32(A, 0);
                int j = 1;
                for (; j + 1 < nb32; j += 2) {
                    FC_LOAD32(B, j * 32);
                    FC_FMA32(A);
                    FC_LOAD32(A, (j + 1) * 32);
                    FC_FMA32(B);
                }
                if (j < nb32) {
                    FC_LOAD32(B, j * 32);
                    FC_FMA32(A);
                    FC_FMA32(B);
                } else {
                    FC_FMA32(A);
                }
                k = nb32 * 32;
            }
            {                                         // tail 0..31: batch-preload then asc chain
                const int rem = nn2 - k;
                float t[31];
                #pragma unroll
                for (int q = 0; q < 31; ++q) {
                    if (q < rem) {
                        const int o_ = RFL(list2i[k + q]);
                        t[q] = *(const float*)(fcb + (size_t)(unsigned)(o_ + coff));
                    } else t[q] = 0.f;
                }
                #pragma unroll
                for (int q = 0; q < 31; ++q)
                    if (q < rem) acc = __fmaf_rn(1.0f, t[q], acc);
            }
#undef FC_LOAD32
#undef FC_FMA32

            const float inp = __fadd_rn(acc, bfc_r);
            const float vd  = __fadd_rn(vL3, __fmul_rn(CM, __fsub_rn(iL3, vL3)));
            const float id  = __fmul_rn(iL3, CS);
            const int z = (__fsub_rn(vd, 1.0f) > 0.0f);
            vL3 = z ? 0.f : vd;
            iL3 = __fadd_rn(id, inp);
            const unsigned long long m = __ballot(z); // full-word overwrite, no atomics
            if ((tid & 63) == 0) {
                bm3[(tid >> 5)]     = (unsigned int)m;
                bm3[(tid >> 5) + 1] = (unsigned int)(m >> 32);
            }
        }
        __syncthreads();   // (F) bm3 complete

        // ---- scan3 (single wave, shuffle prefix): bm3 -> list3s ----
        if (tid < 64) {
            unsigned int bits = (tid < 16) ? bm3[tid] : 0u;
            int cnt = __popc(bits);
            int inc = cnt;
            #pragma unroll
            for (int d = 1; d < 16; d <<= 1) {
                int n = __shfl_up(inc, d);
                if (tid >= d) inc += n;
            }
            int off = inc - cnt;
            if (tid == 15) nn3s = inc;
            while (bits) {
                const int bb = __builtin_ctz(bits);
                bits &= bits - 1;
                list3s[off++] = (unsigned short)(tid * 32 + bb);
            }
        }
        __syncthreads();   // (H) list3s ready

        // ========== output LI cell (strict) — threads 500-509; overlaps next conv1 ==========
        {
            const int otid = tid - 500;
            if (otid >= 0 && otid < 10) {
                const float* wrow_ = woutL + otid * 500;
                const int nn3 = nn3s;
                float acc = 0.f;
                int k = 0;
                const int kfull = nn3 & ~7;
                if (kfull > 0) {                      // 8-wide, 2-deep pipeline (LDS)
                    float a[8];
                    #pragma unroll
                    for (int q = 0; q < 8; ++q)
                        a[q] = wrow_[list3s[q]];
                    for (k = 8; k < kfull; k += 8) {
                        float bv[8];
                        #pragma unroll
                        for (int q = 0; q < 8; ++q)
                            bv[q] = wrow_[list3s[k + q]];
                        #pragma unroll
                        for (int q = 0; q < 8; ++q)
                            acc = __fmaf_rn(1.0f, a[q], acc);
                        #pragma unroll
                        for (int q = 0; q < 8; ++q)
                            a[q] = bv[q];
                    }
                    #pragma unroll
                    for (int q = 0; q < 8; ++q)
                        acc = __fmaf_rn(1.0f, a[q], acc);
                    k = kfull;
                }
                {
                    const int rem = nn3 - k;
                    float t[7];
                    #pragma unroll
                    for (int q = 0; q < 7; ++q)
                        t[q] = (q < rem) ? wrow_[list3s[k + q]] : 0.f;
                    #pragma unroll
                    for (int q = 0; q < 7; ++q)
                        if (q < rem) acc = __fmaf_rn(1.0f, t[q], acc);
                }
                const float vn = __fadd_rn(vO, __fmul_rn(CM, __fsub_rn(iO, vO)));
                iO = __fadd_rn(__fmul_rn(iO, CS), acc);
                vO = vn;
                out[((size_t)ts * NB + b) * 10 + otid] = vn;
            }
        }
        // no end barrier: out-stage reads (list3s, nn3s, woutL) are not rewritten
        // until after barriers B..F of step s+1, which wave 7 must also cross.
    }
}

extern "C" void kernel_launch(void* const* d_in, const int* in_sizes, int n_in,
                              void* d_out, int out_size, void* d_ws, size_t ws_size,
                              hipStream_t stream)
{
    const float* x    = (const float*)d_in[0];
    const float* w1   = (const float*)d_in[1];
    const float* b1   = (const float*)d_in[2];
    const float* w2   = (const float*)d_in[3];
    const float* b2   = (const float*)d_in[4];
    const float* wfc  = (const float*)d_in[5];
    const float* bfc  = (const float*)d_in[6];
    const float* wout = (const float*)d_in[7];
    float* out = (float*)d_out;

    const float* fcptr = wfc;
    long sj = 1, so = 800;
    if (ws_size >= (size_t)500 * 800 * sizeof(float)) {
        float* wfcT = (float*)d_ws;
        transpose_wfc<<<(500 * 800 + 255) / 256, 256, 0, stream>>>(wfc, wfcT);
        fcptr = wfcT; sj = 500; so = 1;
    }

    snn_forward<<<NB, 512, 0, stream>>>(x, w1, b1, w2, b2, fcptr, sj, so, bfc, wout, out);
}